// Round 8
// baseline (474.809 us; speedup 1.0000x reference)
//
#include <hip/hip_runtime.h>
#include <hip/hip_cooperative_groups.h>

namespace cg = cooperative_groups;

#define NN 100000
#define NE 1600000
#define NCH 391             // #chunks == #buckets (256 dst nodes each)
#define CSTRIDE 392
#define CHUNK 4096

static __device__ __forceinline__ unsigned short f2bf(float f) {
    unsigned u = __float_as_uint(f);
    u += 0x7fffu + ((u >> 16) & 1u);   // RNE
    return (unsigned short)(u >> 16);
}

// ---- cooperative CSR build: hist + offsets + place + per-bucket CSR ----
__global__ __launch_bounds__(256) void coop_csr(
        const int* __restrict__ src, const int* __restrict__ dst,
        int* __restrict__ C,      // [NCH][CSTRIDE] chunk-major histogram rows
        int* __restrict__ CO,     // [NCH][CSTRIDE] bucket-major offset rows
        int* __restrict__ tbl,    // [NCH] bucket totals
        int* __restrict__ bbase,  // [NCH+1] bucket bases
        int* __restrict__ pairs, int* __restrict__ esrc,
        int* __restrict__ next, float* __restrict__ dinv) {
    cg::grid_group grid = cg::this_grid();
    __shared__ int sA[512];
    __shared__ int sB[256];
    __shared__ int sC[256];
    __shared__ int stot;
    int t = threadIdx.x;
    int blk = blockIdx.x;

    // ---- P1: chunk histogram -> C[blk][*] (coalesced row write) ----
    sA[t] = 0; sA[t + 256] = 0;
    __syncthreads();
    {
        int base = blk * CHUNK;
        int end = min(base + CHUNK, NE);
        for (int e = base + t; e < end; e += 256) atomicAdd(&sA[dst[e] >> 8], 1);
    }
    __syncthreads();
    C[blk * CSTRIDE + t] = sA[t];
    if (t + 256 < CSTRIDE) C[blk * CSTRIDE + t + 256] = sA[t + 256];
    grid.sync();

    // ---- P2a: block blk = bucket blk: scan column C[*][blk] ----
    {
        int v0 = C[t * CSTRIDE + blk];                       // c = 0..255
        int c2 = t + 256;
        int v1 = (c2 < NCH) ? C[c2 * CSTRIDE + blk] : 0;     // c = 256..390
        sA[t] = v0; sA[t + 256] = v1;
    }
    __syncthreads();
    int a0 = sA[2 * t], a1 = sA[2 * t + 1];
    int ps = a0 + a1;
    sB[t] = ps;
    __syncthreads();
    int pi = 0;   // 0: current in sB, 1: in sC
    for (int off = 1; off < 256; off <<= 1) {
        int cur = (pi == 0) ? sB[t] : sC[t];
        int add = (t >= off) ? ((pi == 0) ? sB[t - off] : sC[t - off]) : 0;
        if (pi == 0) sC[t] = cur + add; else sB[t] = cur + add;
        pi ^= 1;
        __syncthreads();
    }
    int pincl = (pi == 0) ? sB[t] : sC[t];
    int pex = pincl - ps;
    if (t == 255) stot = pincl;
    __syncthreads();
    sA[2 * t]     = pex;        // exclusive within-bucket prefix by chunk
    sA[2 * t + 1] = pex + a0;
    if (t == 0) tbl[blk] = 0;   // placeholder; real write below
    __syncthreads();
    if (t == 0) tbl[blk] = stot;
    grid.sync();

    // ---- P2b: bucket base prefix + write offset row CO[blk][*] ----
    {
        int part = 0;
        for (int i = t; i < blk; i += 256) part += tbl[i];
        sB[t] = part;
        __syncthreads();
        for (int off = 128; off > 0; off >>= 1) {
            if (t < off) sB[t] += sB[t + off];
            __syncthreads();
        }
        int bb = sB[0];
        if (t == 0) {
            bbase[blk] = bb;
            if (blk == NCH - 1) bbase[NCH] = bb + stot;
        }
        CO[blk * CSTRIDE + t] = bb + sA[t];
        int c2 = t + 256;
        if (c2 < NCH) CO[blk * CSTRIDE + c2] = bb + sA[c2];
    }
    grid.sync();

    // ---- P3: place chunk blk via LDS cursors from column CO[*][blk] ----
    {
        if (t < NCH) sA[t] = CO[t * CSTRIDE + blk];
        int b2 = t + 256;
        if (b2 < NCH) sA[b2] = CO[b2 * CSTRIDE + blk];
    }
    __syncthreads();
    {
        int base = blk * CHUNK;
        int end = min(base + CHUNK, NE);
        for (int e = base + t; e < end; e += 256) {
            int d = dst[e];
            int p = atomicAdd(&sA[d >> 8], 1);
            pairs[p] = src[e] | ((d & 255) << 17);
        }
    }
    grid.sync();

    // ---- P4: per-bucket CSR: next[], dinv[], esrc[] ----
    {
        int e0 = bbase[blk], e1 = bbase[blk + 1];
        sA[t] = 0;
        __syncthreads();
        for (int i = e0 + t; i < e1; i += 256) atomicAdd(&sA[pairs[i] >> 17], 1);
        __syncthreads();
        int v = sA[t];
        sB[t] = v;
        __syncthreads();
        int pi2 = 0;
        for (int off = 1; off < 256; off <<= 1) {
            int cur = (pi2 == 0) ? sB[t] : sC[t];
            int add = (t >= off) ? ((pi2 == 0) ? sB[t - off] : sC[t - off]) : 0;
            if (pi2 == 0) sC[t] = cur + add; else sB[t] = cur + add;
            pi2 ^= 1;
            __syncthreads();
        }
        int incl = (pi2 == 0) ? sB[t] : sC[t];
        int node = blk * 256 + t;
        if (node < NN) {
            next[node] = e0 + incl;
            dinv[node] = rsqrtf((float)v + 1.0f);
        }
        __syncthreads();
        sA[t] = e0 + incl - v;    // per-node cursor
        __syncthreads();
        for (int i = e0 + t; i < e1; i += 256) {
            int w = pairs[i];
            int p = atomicAdd(&sA[w >> 17], 1);
            esrc[p] = w & 0x1FFFF;
        }
    }
}

// ---- GEMM [n,64]@[64,64] -> bf16 g = acc*dinv ----
__global__ __launch_bounds__(256) void gemm64g(const float* __restrict__ X,
                                               const float* __restrict__ W,
                                               const float* __restrict__ dinv,
                                               ushort4* __restrict__ G, int n) {
    __shared__ float4 Ws[64][16];
    __shared__ float  Xs[16][68];
    int tid = threadIdx.x;
    const float4* W4 = (const float4*)W;
    #pragma unroll
    for (int i = tid; i < 64 * 16; i += 256) Ws[i >> 4][i & 15] = W4[i];
    {
        int rr = tid >> 4, q = tid & 15;
        int node = blockIdx.x * 16 + rr;
        float4 v = ((const float4*)(X + (size_t)node * 64))[q];
        *(float4*)&Xs[rr][q * 4] = v;
    }
    __syncthreads();
    int r = tid >> 4, cq = tid & 15;
    float4 acc = {0.f, 0.f, 0.f, 0.f};
    #pragma unroll
    for (int k = 0; k < 64; ++k) {
        float x  = Xs[r][k];
        float4 w = Ws[k][cq];
        acc.x += x * w.x; acc.y += x * w.y; acc.z += x * w.z; acc.w += x * w.w;
    }
    int node = blockIdx.x * 16 + r;
    float dd = dinv[node];
    ushort4 pk;
    pk.x = f2bf(acc.x * dd); pk.y = f2bf(acc.y * dd);
    pk.z = f2bf(acc.z * dd); pk.w = f2bf(acc.w * dd);
    G[(size_t)node * 16 + cq] = pk;
}

// ---- gather (bf16 operand): agg + self + bias + relu -> fp32 out ----
// one independent wave per dst node — no cross-wave barriers
__global__ __launch_bounds__(256) void gather_bf16(
        const int* __restrict__ next, const int* __restrict__ esrc,
        const float* __restrict__ dinv, const unsigned* __restrict__ G,
        const float* __restrict__ b, float* __restrict__ outH, int n) {
    int node = (int)((blockIdx.x * blockDim.x + threadIdx.x) >> 6);
    if (node >= n) return;
    int lane = threadIdx.x & 63;
    int half = lane >> 5, m = lane & 31;
    int j0 = node ? next[node - 1] : 0;
    int e1 = next[node];
    float ax = 0.f, ay = 0.f;
    int j = j0 + half;
    for (; j + 6 < e1; j += 8) {
        int s0 = esrc[j], s1 = esrc[j + 2], s2 = esrc[j + 4], s3 = esrc[j + 6];
        unsigned u0 = G[s0 * 32 + m];
        unsigned u1 = G[s1 * 32 + m];
        unsigned u2 = G[s2 * 32 + m];
        unsigned u3 = G[s3 * 32 + m];
        ax += __uint_as_float(u0 << 16) + __uint_as_float(u1 << 16)
            + __uint_as_float(u2 << 16) + __uint_as_float(u3 << 16);
        ay += __uint_as_float(u0 & 0xffff0000u) + __uint_as_float(u1 & 0xffff0000u)
            + __uint_as_float(u2 & 0xffff0000u) + __uint_as_float(u3 & 0xffff0000u);
    }
    for (; j < e1; j += 2) {
        unsigned u = G[esrc[j] * 32 + m];
        ax += __uint_as_float(u << 16);
        ay += __uint_as_float(u & 0xffff0000u);
    }
    ax += __shfl_xor(ax, 32);
    ay += __shfl_xor(ay, 32);
    if (half == 0) {
        float dd = dinv[node];
        unsigned us = G[node * 32 + m];          // self: g*dd = h*dinv^2
        ax += __uint_as_float(us << 16);
        ay += __uint_as_float(us & 0xffff0000u);
        float2 bb = ((const float2*)b)[m];
        float2 o;
        o.x = fmaxf(fmaf(ax, dd, bb.x), 0.f);
        o.y = fmaxf(fmaf(ay, dd, bb.y), 0.f);
        ((float2*)(outH + (size_t)node * 64))[m] = o;
    }
}

// ---- gather-2 + FC head fused: single END barrier (not per-iteration) ----
// 4 waves/block, each gathers its node independently; one __syncthreads;
// then 64 threads compute the 4x(64@64x16) FC from LDS.
__global__ __launch_bounds__(256) void gather_fc(
        const int* __restrict__ next, const int* __restrict__ esrc,
        const float* __restrict__ dinv, const unsigned* __restrict__ G,
        const float* __restrict__ b2, const float* __restrict__ Wfc,
        const float* __restrict__ bfc, float* __restrict__ out) {
    __shared__ float Wfs[64 * 17];    // pad 17: lanes c=0..15 conflict-free
    __shared__ float h2s[4][68];
    int tid = threadIdx.x;
    #pragma unroll
    for (int i = tid; i < 1024; i += 256) {
        int k = i >> 4, c = i & 15;
        Wfs[k * 17 + c] = Wfc[i];
    }
    int w = tid >> 6, lane = tid & 63, half = lane >> 5, m = lane & 31;
    int node = blockIdx.x * 4 + w;
    if (node < NN) {
        int j0 = node ? next[node - 1] : 0;
        int e1 = next[node];
        float ax = 0.f, ay = 0.f;
        int j = j0 + half;
        for (; j + 6 < e1; j += 8) {
            int s0 = esrc[j], s1 = esrc[j + 2], s2 = esrc[j + 4], s3 = esrc[j + 6];
            unsigned u0 = G[s0 * 32 + m];
            unsigned u1 = G[s1 * 32 + m];
            unsigned u2 = G[s2 * 32 + m];
            unsigned u3 = G[s3 * 32 + m];
            ax += __uint_as_float(u0 << 16) + __uint_as_float(u1 << 16)
                + __uint_as_float(u2 << 16) + __uint_as_float(u3 << 16);
            ay += __uint_as_float(u0 & 0xffff0000u) + __uint_as_float(u1 & 0xffff0000u)
                + __uint_as_float(u2 & 0xffff0000u) + __uint_as_float(u3 & 0xffff0000u);
        }
        for (; j < e1; j += 2) {
            unsigned u = G[esrc[j] * 32 + m];
            ax += __uint_as_float(u << 16);
            ay += __uint_as_float(u & 0xffff0000u);
        }
        ax += __shfl_xor(ax, 32);
        ay += __shfl_xor(ay, 32);
        if (half == 0) {
            float dd = dinv[node];
            unsigned us = G[node * 32 + m];
            ax += __uint_as_float(us << 16);
            ay += __uint_as_float(us & 0xffff0000u);
            float2 bb = ((const float2*)b2)[m];
            h2s[w][2 * m]     = fmaxf(fmaf(ax, dd, bb.x), 0.f);
            h2s[w][2 * m + 1] = fmaxf(fmaf(ay, dd, bb.y), 0.f);
        }
    }
    __syncthreads();
    if (tid < 64) {
        int w2 = tid >> 4, c = tid & 15;
        int n2 = blockIdx.x * 4 + w2;
        if (n2 < NN) {
            float acc = bfc[c];
            #pragma unroll
            for (int k = 0; k < 64; ++k)
                acc = fmaf(h2s[w2][k], Wfs[k * 17 + c], acc);
            out[n2 * 16 + c] = acc;
        }
    }
}

extern "C" void kernel_launch(void* const* d_in, const int* in_sizes, int n_in,
                              void* d_out, int out_size, void* d_ws, size_t ws_size,
                              hipStream_t stream) {
    const float* x   = (const float*)d_in[0];
    const int*   ei  = (const int*)d_in[1];
    const float* W1  = (const float*)d_in[2];
    const float* b1  = (const float*)d_in[3];
    const float* W2  = (const float*)d_in[4];
    const float* b2  = (const float*)d_in[5];
    const float* Wfc = (const float*)d_in[6];
    const float* bfc = (const float*)d_in[7];
    float* out = (float*)d_out;

    const int* src = ei;
    const int* dst = ei + NE;

    // ws: dinv[NN] | bbase[392] | tbl[392] | next[NN] | C[391*392] | CO[391*392]
    //     | esrc[NE] | G[NN*32 u, 12.8MB] | bufB[NN*64 f32, 25.6MB]   (~47 MB)
    // pairs aliases bufB (consumed inside coop_csr before gather-1 writes bufB)
    float*    dinv  = (float*)d_ws;
    int*      bbase = (int*)(dinv + NN);
    int*      tbl   = bbase + CSTRIDE;
    int*      next  = tbl + CSTRIDE;
    int*      C     = next + NN;
    int*      CO    = C + NCH * CSTRIDE;
    int*      esrc  = CO + NCH * CSTRIDE;
    unsigned* G     = (unsigned*)(esrc + NE);
    float*    bufB  = (float*)(G + (size_t)NN * 32);
    int*      pairs = (int*)bufB;

    // ---- CSR build: ONE cooperative dispatch ----
    void* args[] = {(void*)&src, (void*)&dst, (void*)&C, (void*)&CO, (void*)&tbl,
                    (void*)&bbase, (void*)&pairs, (void*)&esrc, (void*)&next, (void*)&dinv};
    hipLaunchCooperativeKernel((void*)coop_csr, dim3(NCH), dim3(256), args, 0, stream);

    // ---- layer 1 ----
    gemm64g<<<NN / 16, 256, 0, stream>>>(x, W1, dinv, (ushort4*)G, NN);
    gather_bf16<<<(NN * 64) / 256, 256, 0, stream>>>(next, esrc, dinv, G, b1, bufB, NN);

    // ---- layer 2 + FC head ----
    gemm64g<<<NN / 16, 256, 0, stream>>>(bufB, W2, dinv, (ushort4*)G, NN);
    gather_fc<<<(NN + 3) / 4, 256, 0, stream>>>(next, esrc, dinv, G, b2, Wfc, bfc, out);
}

// Round 9
// 312.027 us; speedup vs baseline: 1.5217x; 1.5217x over previous
//
#include <hip/hip_runtime.h>

#define NN 100000
#define NE 1600000
#define NB 391              // ceil(NN/256) node-buckets of 256 dst nodes
#define NBP 512             // padded bucket count (pow2 for scans)
#define CHUNK 8192
#define NCHUNK ((NE + CHUNK - 1) / CHUNK)   // 196

static __device__ __forceinline__ unsigned short f2bf(float f) {
    unsigned u = __float_as_uint(f);
    u += 0x7fffu + ((u >> 16) & 1u);   // RNE
    return (unsigned short)(u >> 16);
}

// ---------------- A0: zero bucket counters ----------------
__global__ void zero_bkt(int* __restrict__ cnt) {
    int t = blockIdx.x * blockDim.x + threadIdx.x;
    if (t < NBP) cnt[t] = 0;
}

// ---------------- A1: bucket histogram (LDS-combined) ----------------
__global__ __launch_bounds__(256) void bkt_hist(const int* __restrict__ dst,
                                                int* __restrict__ cnt) {
    __shared__ int h[NBP];
    int t = threadIdx.x;
    for (int i = t; i < NBP; i += 256) h[i] = 0;
    __syncthreads();
    int base = blockIdx.x * CHUNK;
    int end = min(base + CHUNK, NE);
    for (int e = base + t; e < end; e += 256) atomicAdd(&h[dst[e] >> 8], 1);
    __syncthreads();
    for (int i = t; i < NBP; i += 256) if (h[i]) atomicAdd(&cnt[i], h[i]);
}

// ---------------- A2: scan bucket counts -> base, next ----------------
__global__ __launch_bounds__(512) void bkt_scan(const int* __restrict__ cnt,
                                                int* __restrict__ base,
                                                int* __restrict__ nxt) {
    __shared__ int buf[2][512];
    int t = threadIdx.x;
    int v = cnt[t];
    int pi = 0;
    buf[0][t] = v;
    __syncthreads();
    for (int off = 1; off < 512; off <<= 1) {
        int add = (t >= off) ? buf[pi][t - off] : 0;
        buf[1 - pi][t] = buf[pi][t] + add;
        pi ^= 1;
        __syncthreads();
    }
    int ex = buf[pi][t] - v;
    base[t] = ex;
    nxt[t] = ex;
    if (t == 511) base[512] = buf[pi][511];   // == NE
}

// ---------------- A3: bucket placement with LDS binning ----------------
__global__ __launch_bounds__(512) void bkt_place(const int* __restrict__ src,
                                                 const int* __restrict__ dst,
                                                 int* __restrict__ bnext,
                                                 int* __restrict__ pairs) {
    __shared__ int stage[CHUNK];     // packed src | dstLow<<17
    __shared__ int sbuf[2][512];
    __shared__ int lcnt[512];
    __shared__ int lex[512];
    __shared__ int gbase[512];
    __shared__ int lnext[512];
    int t = threadIdx.x;
    int base = blockIdx.x * CHUNK;
    int end = min(base + CHUNK, NE);
    int cc = end - base;
    lcnt[t] = 0;
    __syncthreads();
    for (int e = base + t; e < end; e += 512) atomicAdd(&lcnt[dst[e] >> 8], 1);
    __syncthreads();
    int v = lcnt[t];
    int pi = 0;
    sbuf[0][t] = v;
    __syncthreads();
    for (int off = 1; off < 512; off <<= 1) {
        int add = (t >= off) ? sbuf[pi][t - off] : 0;
        sbuf[1 - pi][t] = sbuf[pi][t] + add;
        pi ^= 1;
        __syncthreads();
    }
    int ex = sbuf[pi][t] - v;
    lex[t] = ex;
    lnext[t] = ex;
    gbase[t] = v ? atomicAdd(&bnext[t], v) : 0;
    __syncthreads();
    for (int e = base + t; e < end; e += 512) {
        int d = dst[e];
        int b = d >> 8;
        int r = atomicAdd(&lnext[b], 1);
        stage[r] = src[e] | ((d & 255) << 17);
    }
    __syncthreads();
    for (int i = t; i < cc; i += 512) {
        int lo = 0, hi = 511;
        while (lo < hi) {
            int mid = (lo + hi + 1) >> 1;
            if (lex[mid] <= i) lo = mid; else hi = mid - 1;
        }
        pairs[gbase[lo] + (i - lex[lo])] = stage[i];
    }
}

// ---------------- B: per-bucket CSR build + dinv ----------------
__global__ __launch_bounds__(256) void bkt_csr(const int* __restrict__ pairs,
                                               const int* __restrict__ base,
                                               int* __restrict__ next,
                                               float* __restrict__ dinv,
                                               int* __restrict__ esrc) {
    __shared__ int cnt[256];
    __shared__ int sbuf[2][256];
    __shared__ int nxt[256];
    int b = blockIdx.x;
    int e0 = base[b], e1 = base[b + 1];
    int t = threadIdx.x;
    cnt[t] = 0;
    __syncthreads();
    for (int i = e0 + t; i < e1; i += 256) atomicAdd(&cnt[pairs[i] >> 17], 1);
    __syncthreads();
    int v = cnt[t];
    int pi = 0; sbuf[0][t] = v; __syncthreads();
    for (int off = 1; off < 256; off <<= 1) {
        int add = (t >= off) ? sbuf[pi][t - off] : 0;
        sbuf[1 - pi][t] = sbuf[pi][t] + add;
        pi ^= 1;
        __syncthreads();
    }
    int incl = sbuf[pi][t];
    int node = b * 256 + t;
    if (node < NN) {
        next[node] = e0 + incl;
        dinv[node] = rsqrtf((float)v + 1.0f);
    }
    nxt[t] = e0 + incl - v;
    __syncthreads();
    for (int i = e0 + t; i < e1; i += 256) {
        int w = pairs[i];
        int p = atomicAdd(&nxt[w >> 17], 1);
        esrc[p] = w & 0x1FFFF;
    }
}

// ---------------- GEMM [n,64]@[64,64] -> bf16 g = acc*dinv ----------------
__global__ __launch_bounds__(256) void gemm64g(const float* __restrict__ X,
                                               const float* __restrict__ W,
                                               const float* __restrict__ dinv,
                                               ushort4* __restrict__ G, int n) {
    __shared__ float4 Ws[64][16];
    __shared__ float  Xs[16][68];
    int tid = threadIdx.x;
    const float4* W4 = (const float4*)W;
    #pragma unroll
    for (int i = tid; i < 64 * 16; i += 256) Ws[i >> 4][i & 15] = W4[i];
    {
        int rr = tid >> 4, q = tid & 15;
        int node = blockIdx.x * 16 + rr;
        float4 v = ((const float4*)(X + (size_t)node * 64))[q];
        *(float4*)&Xs[rr][q * 4] = v;
    }
    __syncthreads();
    int r = tid >> 4, cq = tid & 15;
    float4 acc = {0.f, 0.f, 0.f, 0.f};
    #pragma unroll
    for (int k = 0; k < 64; ++k) {
        float x  = Xs[r][k];
        float4 w = Ws[k][cq];
        acc.x += x * w.x; acc.y += x * w.y; acc.z += x * w.z; acc.w += x * w.w;
    }
    int node = blockIdx.x * 16 + r;
    float dd = dinv[node];
    ushort4 pk;
    pk.x = f2bf(acc.x * dd); pk.y = f2bf(acc.y * dd);
    pk.z = f2bf(acc.z * dd); pk.w = f2bf(acc.w * dd);
    G[(size_t)node * 16 + cq] = pk;
}

// ---------------- gather (bf16): agg + self + bias + relu -> fp32 ----------------
// one independent wave per dst node — no cross-wave barriers
__global__ __launch_bounds__(256) void gather_bf16(
        const int* __restrict__ next, const int* __restrict__ esrc,
        const float* __restrict__ dinv, const unsigned* __restrict__ G,
        const float* __restrict__ b, float* __restrict__ outH, int n) {
    int node = (int)((blockIdx.x * blockDim.x + threadIdx.x) >> 6);
    if (node >= n) return;
    int lane = threadIdx.x & 63;
    int half = lane >> 5, m = lane & 31;
    int j0 = node ? next[node - 1] : 0;
    int e1 = next[node];
    float ax = 0.f, ay = 0.f;
    int j = j0 + half;
    for (; j + 6 < e1; j += 8) {
        int s0 = esrc[j], s1 = esrc[j + 2], s2 = esrc[j + 4], s3 = esrc[j + 6];
        unsigned u0 = G[s0 * 32 + m];
        unsigned u1 = G[s1 * 32 + m];
        unsigned u2 = G[s2 * 32 + m];
        unsigned u3 = G[s3 * 32 + m];
        ax += __uint_as_float(u0 << 16) + __uint_as_float(u1 << 16)
            + __uint_as_float(u2 << 16) + __uint_as_float(u3 << 16);
        ay += __uint_as_float(u0 & 0xffff0000u) + __uint_as_float(u1 & 0xffff0000u)
            + __uint_as_float(u2 & 0xffff0000u) + __uint_as_float(u3 & 0xffff0000u);
    }
    for (; j < e1; j += 2) {
        unsigned u = G[esrc[j] * 32 + m];
        ax += __uint_as_float(u << 16);
        ay += __uint_as_float(u & 0xffff0000u);
    }
    ax += __shfl_xor(ax, 32);
    ay += __shfl_xor(ay, 32);
    if (half == 0) {
        float dd = dinv[node];
        unsigned us = G[node * 32 + m];          // self: g*dd = h*dinv^2
        ax += __uint_as_float(us << 16);
        ay += __uint_as_float(us & 0xffff0000u);
        float2 bb = ((const float2*)b)[m];
        float2 o;
        o.x = fmaxf(fmaf(ax, dd, bb.x), 0.f);
        o.y = fmaxf(fmaf(ay, dd, bb.y), 0.f);
        ((float2*)(outH + (size_t)node * 64))[m] = o;
    }
}

// ---------------- gather-2 + FC head fused: single END barrier ----------------
// 4 waves/block gather independently; one __syncthreads; 64 threads do the FC.
__global__ __launch_bounds__(256) void gather_fc(
        const int* __restrict__ next, const int* __restrict__ esrc,
        const float* __restrict__ dinv, const unsigned* __restrict__ G,
        const float* __restrict__ b2, const float* __restrict__ Wfc,
        const float* __restrict__ bfc, float* __restrict__ out) {
    __shared__ float Wfs[64 * 17];    // pad 17: FC lanes conflict-free
    __shared__ float h2s[4][68];
    int tid = threadIdx.x;
    #pragma unroll
    for (int i = tid; i < 1024; i += 256) {
        int k = i >> 4, c = i & 15;
        Wfs[k * 17 + c] = Wfc[i];
    }
    int w = tid >> 6, lane = tid & 63, half = lane >> 5, m = lane & 31;
    int node = blockIdx.x * 4 + w;
    if (node < NN) {
        int j0 = node ? next[node - 1] : 0;
        int e1 = next[node];
        float ax = 0.f, ay = 0.f;
        int j = j0 + half;
        for (; j + 6 < e1; j += 8) {
            int s0 = esrc[j], s1 = esrc[j + 2], s2 = esrc[j + 4], s3 = esrc[j + 6];
            unsigned u0 = G[s0 * 32 + m];
            unsigned u1 = G[s1 * 32 + m];
            unsigned u2 = G[s2 * 32 + m];
            unsigned u3 = G[s3 * 32 + m];
            ax += __uint_as_float(u0 << 16) + __uint_as_float(u1 << 16)
                + __uint_as_float(u2 << 16) + __uint_as_float(u3 << 16);
            ay += __uint_as_float(u0 & 0xffff0000u) + __uint_as_float(u1 & 0xffff0000u)
                + __uint_as_float(u2 & 0xffff0000u) + __uint_as_float(u3 & 0xffff0000u);
        }
        for (; j < e1; j += 2) {
            unsigned u = G[esrc[j] * 32 + m];
            ax += __uint_as_float(u << 16);
            ay += __uint_as_float(u & 0xffff0000u);
        }
        ax += __shfl_xor(ax, 32);
        ay += __shfl_xor(ay, 32);
        if (half == 0) {
            float dd = dinv[node];
            unsigned us = G[node * 32 + m];
            ax += __uint_as_float(us << 16);
            ay += __uint_as_float(us & 0xffff0000u);
            float2 bb = ((const float2*)b2)[m];
            h2s[w][2 * m]     = fmaxf(fmaf(ax, dd, bb.x), 0.f);
            h2s[w][2 * m + 1] = fmaxf(fmaf(ay, dd, bb.y), 0.f);
        }
    }
    __syncthreads();
    if (tid < 64) {
        int w2 = tid >> 4, c = tid & 15;
        int n2 = blockIdx.x * 4 + w2;
        if (n2 < NN) {
            float acc = bfc[c];
            #pragma unroll
            for (int k = 0; k < 64; ++k)
                acc = fmaf(h2s[w2][k], Wfs[k * 17 + c], acc);
            out[n2 * 16 + c] = acc;
        }
    }
}

extern "C" void kernel_launch(void* const* d_in, const int* in_sizes, int n_in,
                              void* d_out, int out_size, void* d_ws, size_t ws_size,
                              hipStream_t stream) {
    const float* x   = (const float*)d_in[0];
    const int*   ei  = (const int*)d_in[1];
    const float* W1  = (const float*)d_in[2];
    const float* b1  = (const float*)d_in[3];
    const float* W2  = (const float*)d_in[4];
    const float* b2  = (const float*)d_in[5];
    const float* Wfc = (const float*)d_in[6];
    const float* bfc = (const float*)d_in[7];
    float* out = (float*)d_out;

    const int* src = ei;
    const int* dst = ei + NE;

    // ws: dinv[NN] | bcnt[512] | bbase[513] | bnext[512] | next[NN] | esrc[NE]
    //     | G[NN*32 u, 12.8MB] | bufB[NN*64 f32, 25.6MB]   (~46 MB)
    // pairs aliases bufB (consumed by bkt_csr before gather-1 writes bufB)
    float*    dinv  = (float*)d_ws;
    int*      bcnt  = (int*)(dinv + NN);
    int*      bbase = bcnt + NBP;
    int*      bnext = bbase + NBP + 1;
    int*      next  = bnext + NBP;
    int*      esrc  = next + NN;
    unsigned* G     = (unsigned*)(esrc + NE);
    float*    bufB  = (float*)(G + (size_t)NN * 32);
    int*      pairs = (int*)bufB;

    // ---- CSR build (R5-proven two-pass counting sort) ----
    zero_bkt<<<2, 256, 0, stream>>>(bcnt);
    bkt_hist<<<NCHUNK, 256, 0, stream>>>(dst, bcnt);
    bkt_scan<<<1, 512, 0, stream>>>(bcnt, bbase, bnext);
    bkt_place<<<NCHUNK, 512, 0, stream>>>(src, dst, bnext, pairs);
    bkt_csr<<<NB, 256, 0, stream>>>(pairs, bbase, next, dinv, esrc);

    // ---- layer 1 ----
    gemm64g<<<NN / 16, 256, 0, stream>>>(x, W1, dinv, (ushort4*)G, NN);
    gather_bf16<<<(NN * 64) / 256, 256, 0, stream>>>(next, esrc, dinv, G, b1, bufB, NN);

    // ---- layer 2 + FC head (fused) ----
    gemm64g<<<NN / 16, 256, 0, stream>>>(bufB, W2, dinv, (ushort4*)G, NN);
    gather_fc<<<(NN + 3) / 4, 256, 0, stream>>>(next, esrc, dinv, G, b2, Wfc, bfc, out);
}